// Round 10
// baseline (135.653 us; speedup 1.0000x reference)
//
#include <hip/hip_runtime.h>
#include <math.h>

#define PP 7
#define CCH 256

// Fractional per-pixel coverage at integer column `colf` of interval [a,b].
__device__ __forceinline__ float coverage(float colf, float a, float b) {
    float af = floorf(a);
    float bc = ceilf(b);
    float v  = (colf >= af && colf < bc) ? 1.0f : 0.0f;
    float wl = (colf == af) ? (1.0f + af - a) : 1.0f;
    float wr = (colf == bc - 1.0f) ? (1.0f + b - bc) : 1.0f;
    return v * wl * wr;
}

// ---------------- fused NCHW -> NHWC transpose, all 4 levels, float4 both sides ----------------
__global__ __launch_bounds__(256) void nchw_to_nhwc_all(
    const float* __restrict__ f0, const float* __restrict__ f1,
    const float* __restrict__ f2, const float* __restrict__ f3,
    float* __restrict__ w0, float* __restrict__ w1,
    float* __restrict__ w2, float* __restrict__ w3, int NIMG)
{
    __shared__ float tile[64][65];
    int b = blockIdx.x;
    const float* src; float* dst; int HW, hw64;
    const int t0 = NIMG * 1024, t1 = t0 + NIMG * 256, t2 = t1 + NIMG * 64;
    if (b < t0)      {          src = f0; dst = w0; HW = 16384; hw64 = 256; }
    else if (b < t1) { b -= t0; src = f1; dst = w1; HW = 4096;  hw64 = 64;  }
    else if (b < t2) { b -= t1; src = f2; dst = w2; HW = 1024;  hw64 = 16;  }
    else             { b -= t2; src = f3; dst = w3; HW = 256;   hw64 = 4;   }
    const int tpi  = hw64 * 4;
    const int n    = b / tpi;
    const int r    = b - n * tpi;
    const int cb   = r / hw64;
    const int pix0 = (r - cb * hw64) * 64;
    const int c0   = cb * 64;

    const int tid = threadIdx.x;

    // load phase: float4 of pixels; lanes 0..15 contiguous pixel-quads of one channel
    {
        const int pq = tid & 15;          // pixel quad 0..15
        const int chb = tid >> 4;         // 0..15
        const float* s = src + ((size_t)n * CCH + c0) * HW + pix0 + 4*pq;
        #pragma unroll
        for (int it = 0; it < 4; ++it) {
            const int ch = chb + it*16;
            const float4 v = *(const float4*)(s + (size_t)ch * HW);
            tile[ch][4*pq+0] = v.x;
            tile[ch][4*pq+1] = v.y;
            tile[ch][4*pq+2] = v.z;
            tile[ch][4*pq+3] = v.w;
        }
    }
    __syncthreads();
    // store phase: float4 of channels; lanes 0..15 cover 256B of one pixel
    {
        const int tc = tid & 15;          // channel quad 0..15
        const int pb2 = tid >> 4;         // 0..15
        float* d = dst + ((size_t)n * HW + pix0) * CCH + c0 + 4*tc;
        #pragma unroll
        for (int it = 0; it < 4; ++it) {
            const int p = pb2 + it*16;
            float4 v;
            v.x = tile[4*tc+0][p];
            v.y = tile[4*tc+1][p];
            v.z = tile[4*tc+2][p];
            v.w = tile[4*tc+3][p];
            *(float4*)(d + (size_t)p * CCH) = v;
        }
    }
}

// ---------------- gather: block = (pair k, channel half); wave = py; lane = channel-pair ----------------
__global__ __launch_bounds__(448) void roi_gather_nhwc(
    const float* __restrict__ n0, const float* __restrict__ n1,
    const float* __restrict__ n2, const float* __restrict__ n3,
    const float* __restrict__ bh, const float* __restrict__ bo,
    float* __restrict__ out, int K)
{
    const int k    = blockIdx.x;
    const int half = blockIdx.y;         // channels [half*128, half*128+128)
    const int tid  = threadIdx.x;        // 0..447
    const int wpy  = tid >> 6;           // wave id == output bin row 0..6
    const int lane = tid & 63;           // channel pair within half: ch = half*128 + 2*lane

    __shared__ float stage[128 * 49];                // 25088 B; flat == out[k] half-slice
    __shared__ float wbin[49][16];                   // per-bin corner weights
    __shared__ int   t_xoff_lo[14], t_xoff_hi[14];   // x*256
    __shared__ int   s_yoff_lo[14], s_yoff_hi[14];   // y*W*256
    __shared__ float t_wxl[14], t_wxh[14], t_cxu0[14], t_cxu1[14], t_cxo0[14], t_cxo1[14];
    __shared__ float t_wyl[14], t_wyh[14], t_cyu0[14], t_cyu1[14], t_cyo0[14], t_cyo1[14];

    // ---- per-box uniform scalar metadata ----
    const float hx1 = bh[k*5+1], hy1 = bh[k*5+2], hx2 = bh[k*5+3], hy2 = bh[k*5+4];
    const float px1 = bo[k*5+1], py1 = bo[k*5+2], px2 = bo[k*5+3], py2 = bo[k*5+4];
    const int   bimg = (int)bh[k*5+0];

    const float ux1 = fminf(hx1, px1), uy1 = fminf(hy1, py1);
    const float ux2 = fmaxf(hx2, px2), uy2 = fmaxf(hy2, py2);
    const float su = sqrtf((ux2-ux1)*(uy2-uy1));
    const float so = sqrtf((px2-px1)*(py2-py1));
    const float s  = fminf(su, so);
    float lvf = floorf(4.0f + log2f(s/224.0f + 1e-6f));
    lvf = fminf(fmaxf(lvf, 2.0f), 5.0f);
    const int lv = (int)lvf - 2;

    const float scales[4] = {0.25f, 0.125f, 0.0625f, 0.03125f};
    const int   dims[4]   = {128, 64, 32, 16};
    const float scale = scales[lv];
    const int   W = dims[lv], H = W;
    const int   HW = W * H;
    const float Wf = (float)W, Hf = (float)H;
    const float* nh = (lv == 0) ? n0 : (lv == 1) ? n1 : (lv == 2) ? n2 : n3;

    const float usx1 = ux1*scale, usy1 = uy1*scale, usx2 = ux2*scale, usy2 = uy2*scale;
    const float osx1 = px1*scale, osy1 = py1*scale, osx2 = px2*scale, osy2 = py2*scale;
    const float cux1 = fminf(fmaxf(usx1, 0.f), Wf), cux2 = fminf(fmaxf(usx2, 0.f), Wf);
    const float cuy1 = fminf(fmaxf(usy1, 0.f), Hf), cuy2 = fminf(fmaxf(usy2, 0.f), Hf);
    const float cox1 = fminf(fmaxf(osx1, 0.f), Wf), cox2 = fminf(fmaxf(osx2, 0.f), Wf);
    const float coy1 = fminf(fmaxf(osy1, 0.f), Hf), coy2 = fminf(fmaxf(osy2, 0.f), Hf);
    const float roi_w = fmaxf(usx2 - usx1, 1.0f);
    const float roi_h = fmaxf(usy2 - usy1, 1.0f);

    // ---- axis tables (x: wave0 lanes 0..13, y: wave1 lanes 0..13) ----
    if (tid < 14) {
        const int i = tid;
        const float t = (float)(i >> 1) + 0.25f + 0.5f*(float)(i & 1);
        const float p = usx1 + t * (roi_w / 7.0f);
        const float valid = (p >= -1.0f && p <= Wf) ? 1.0f : 0.0f;
        float cc = fmaxf(p, 0.0f);
        const float lo0 = floorf(cc);
        const bool top = (lo0 >= Wf - 1.0f);
        const float lo = top ? (Wf - 1.0f) : lo0;
        const float hi = top ? (Wf - 1.0f) : (lo0 + 1.0f);
        cc = top ? (Wf - 1.0f) : cc;
        const float frac = cc - lo;
        t_xoff_lo[i] = (int)lo * CCH;  t_xoff_hi[i] = (int)hi * CCH;
        t_wxl[i] = (1.0f - frac) * valid;  t_wxh[i] = frac * valid;
        t_cxu0[i] = coverage(lo, cux1, cux2);
        t_cxu1[i] = coverage(hi, cux1, cux2);
        t_cxo0[i] = coverage(lo, cox1, cox2);
        t_cxo1[i] = coverage(hi, cox1, cox2);
    } else if (tid >= 64 && tid < 78) {
        const int i = tid - 64;
        const float t = (float)(i >> 1) + 0.25f + 0.5f*(float)(i & 1);
        const float p = usy1 + t * (roi_h / 7.0f);
        const float valid = (p >= -1.0f && p <= Hf) ? 1.0f : 0.0f;
        float cc = fmaxf(p, 0.0f);
        const float lo0 = floorf(cc);
        const bool top = (lo0 >= Hf - 1.0f);
        const float lo = top ? (Hf - 1.0f) : lo0;
        const float hi = top ? (Hf - 1.0f) : (lo0 + 1.0f);
        cc = top ? (Hf - 1.0f) : cc;
        const float frac = cc - lo;
        s_yoff_lo[i] = (int)lo * W * CCH;  s_yoff_hi[i] = (int)hi * W * CCH;
        t_wyl[i] = (1.0f - frac) * valid;  t_wyh[i] = frac * valid;
        t_cyu0[i] = coverage(lo, cuy1, cuy2);
        t_cyu1[i] = coverage(hi, cuy1, cuy2);
        t_cyo0[i] = coverage(lo, coy1, coy2);
        t_cyo1[i] = coverage(hi, coy1, coy2);
    }
    __syncthreads();

    // ---- per-bin weight table (wave0 lanes 0..48) ----
    if (tid < 49) {
        const int bpy = tid / 7, bpx = tid - bpy * 7;
        #pragma unroll
        for (int isy = 0; isy < 2; ++isy) {
            const int sy = 2*bpy + isy;
            const float wy0 = t_wyl[sy], wy1 = t_wyh[sy];
            const float yu0 = t_cyu0[sy], yu1 = t_cyu1[sy];
            const float yo0 = t_cyo0[sy], yo1 = t_cyo1[sy];
            #pragma unroll
            for (int isx = 0; isx < 2; ++isx) {
                const int sxm = 2*bpx + isx;
                const float wx0 = t_wxl[sxm], wx1 = t_wxh[sxm];
                const float xu0 = t_cxu0[sxm], xu1 = t_cxu1[sxm];
                const float xo0 = t_cxo0[sxm], xo1 = t_cxo1[sxm];
                const int p4 = (isy*2 + isx) * 4;
                wbin[tid][p4+0] = wy0*wx0*fmaxf(yu0*xu0, yo0*xo0);
                wbin[tid][p4+1] = wy0*wx1*fmaxf(yu0*xu1, yo0*xo1);
                wbin[tid][p4+2] = wy1*wx0*fmaxf(yu1*xu0, yo1*xo0);
                wbin[tid][p4+3] = wy1*wx1*fmaxf(yu1*xu1, yo1*xo1);
            }
        }
    }
    __syncthreads();

    // ---- main gather: float2 per (corner, channel-pair); weights from LDS ----
    const float* pb = nh + (size_t)bimg * HW * CCH + half*128 + 2*lane;

    float2 acc[7];
    #pragma unroll
    for (int q = 0; q < 7; ++q) acc[q] = make_float2(0.f, 0.f);

    #pragma unroll
    for (int isy = 0; isy < 2; ++isy) {
        const int sy  = 2*wpy + isy;
        const int yoL = s_yoff_lo[sy], yoH = s_yoff_hi[sy];
        #pragma unroll
        for (int ix = 0; ix < 14; ++ix) {
            const int pxb = ix >> 1, isx = ix & 1;
            const float4 w = *(const float4*)&wbin[wpy*7 + pxb][(isy*2 + isx)*4];
            const int xoL = t_xoff_lo[ix], xoH = t_xoff_hi[ix];
            const float2 vLL = *(const float2*)(pb + yoL + xoL);
            const float2 vLH = *(const float2*)(pb + yoL + xoH);
            const float2 vHL = *(const float2*)(pb + yoH + xoL);
            const float2 vHH = *(const float2*)(pb + yoH + xoH);
            acc[pxb].x += w.x*vLL.x + w.y*vLH.x + w.z*vHL.x + w.w*vHH.x;
            acc[pxb].y += w.x*vLL.y + w.y*vLH.y + w.z*vHL.y + w.w*vHH.y;
        }
    }

    // ---- stage: flat layout == out[k] half-slice (cl*49 + py*7 + px) ----
    {
        const int cl = 2*lane;
        #pragma unroll
        for (int q = 0; q < 7; ++q) {
            const int col = wpy*7 + q;
            stage[(cl+0)*49 + col] = acc[q].x * 0.25f;
            stage[(cl+1)*49 + col] = acc[q].y * 0.25f;
        }
    }
    __syncthreads();

    // ---- single coalesced burst: 6272 floats (= 448 * 14), each line written once ----
    float* ok = out + (size_t)k * (CCH * 49) + (size_t)half * (128 * 49);
    #pragma unroll
    for (int i = 0; i < 14; ++i) {
        const int idx = tid + i*448;
        ok[idx] = stage[idx];
    }
}

// ---------------- fallback: measured-good NCHW direct kernel (291 us) ----------------
__global__ __launch_bounds__(256) void roi_pair_kernel(
    const float* __restrict__ f0, const float* __restrict__ f1,
    const float* __restrict__ f2, const float* __restrict__ f3,
    const float* __restrict__ bh, const float* __restrict__ bo,
    float* __restrict__ out, int K)
{
    const int k  = blockIdx.x;
    const int py = blockIdx.y;
    const int c  = threadIdx.x;

    __shared__ int   t_xlo[14], t_xhi[14];
    __shared__ float t_wxl[14], t_wxh[14], t_cxu0[14], t_cxu1[14], t_cxo0[14], t_cxo1[14];
    __shared__ int   s_ylo[2], s_yhi[2];
    __shared__ float s_wyl[2], s_wyh[2], s_cyu0[2], s_cyu1[2], s_cyo0[2], s_cyo1[2];

    const float hx1 = bh[k*5+1], hy1 = bh[k*5+2], hx2 = bh[k*5+3], hy2 = bh[k*5+4];
    const float px1 = bo[k*5+1], py1 = bo[k*5+2], px2 = bo[k*5+3], py2 = bo[k*5+4];
    const int   bimg = (int)bh[k*5+0];

    const float ux1 = fminf(hx1, px1), uy1 = fminf(hy1, py1);
    const float ux2 = fmaxf(hx2, px2), uy2 = fmaxf(hy2, py2);
    const float su = sqrtf((ux2-ux1)*(uy2-uy1));
    const float so = sqrtf((px2-px1)*(py2-py1));
    const float s  = fminf(su, so);
    float lvf = floorf(4.0f + log2f(s/224.0f + 1e-6f));
    lvf = fminf(fmaxf(lvf, 2.0f), 5.0f);
    const int lv = (int)lvf - 2;

    const float scales[4] = {0.25f, 0.125f, 0.0625f, 0.03125f};
    const int   dims[4]   = {128, 64, 32, 16};
    const float scale = scales[lv];
    const int   W = dims[lv], H = W;
    const float Wf = (float)W, Hf = (float)H;
    const float* feat = (lv == 0) ? f0 : (lv == 1) ? f1 : (lv == 2) ? f2 : f3;

    const float usx1 = ux1*scale, usy1 = uy1*scale, usx2 = ux2*scale, usy2 = uy2*scale;
    const float osx1 = px1*scale, osy1 = py1*scale, osx2 = px2*scale, osy2 = py2*scale;
    const float cux1 = fminf(fmaxf(usx1, 0.f), Wf), cux2 = fminf(fmaxf(usx2, 0.f), Wf);
    const float cuy1 = fminf(fmaxf(usy1, 0.f), Hf), cuy2 = fminf(fmaxf(usy2, 0.f), Hf);
    const float cox1 = fminf(fmaxf(osx1, 0.f), Wf), cox2 = fminf(fmaxf(osx2, 0.f), Wf);
    const float coy1 = fminf(fmaxf(osy1, 0.f), Hf), coy2 = fminf(fmaxf(osy2, 0.f), Hf);
    const float roi_w = fmaxf(usx2 - usx1, 1.0f);
    const float roi_h = fmaxf(usy2 - usy1, 1.0f);

    if (threadIdx.x < 14) {
        const int i = threadIdx.x;
        const float t = (float)(i >> 1) + 0.25f + 0.5f*(float)(i & 1);
        const float p = usx1 + t * (roi_w / 7.0f);
        const float valid = (p >= -1.0f && p <= Wf) ? 1.0f : 0.0f;
        float cc = fmaxf(p, 0.0f);
        const float lo0 = floorf(cc);
        const bool top = (lo0 >= Wf - 1.0f);
        const float lo = top ? (Wf - 1.0f) : lo0;
        const float hi = top ? (Wf - 1.0f) : (lo0 + 1.0f);
        cc = top ? (Wf - 1.0f) : cc;
        const float frac = cc - lo;
        t_xlo[i] = (int)lo;  t_xhi[i] = (int)hi;
        t_wxl[i] = (1.0f - frac) * valid;  t_wxh[i] = frac * valid;
        t_cxu0[i] = coverage(lo, cux1, cux2);
        t_cxu1[i] = coverage(hi, cux1, cux2);
        t_cxo0[i] = coverage(lo, cox1, cox2);
        t_cxo1[i] = coverage(hi, cox1, cox2);
    } else if (threadIdx.x >= 64 && threadIdx.x < 66) {
        const int isy = threadIdx.x - 64;
        const int i = 2*py + isy;
        const float t = (float)(i >> 1) + 0.25f + 0.5f*(float)(i & 1);
        const float p = usy1 + t * (roi_h / 7.0f);
        const float valid = (p >= -1.0f && p <= Hf) ? 1.0f : 0.0f;
        float cc = fmaxf(p, 0.0f);
        const float lo0 = floorf(cc);
        const bool top = (lo0 >= Hf - 1.0f);
        const float lo = top ? (Hf - 1.0f) : lo0;
        const float hi = top ? (Hf - 1.0f) : (lo0 + 1.0f);
        cc = top ? (Hf - 1.0f) : cc;
        const float frac = cc - lo;
        s_ylo[isy] = (int)lo;  s_yhi[isy] = (int)hi;
        s_wyl[isy] = (1.0f - frac) * valid;  s_wyh[isy] = frac * valid;
        s_cyu0[isy] = coverage(lo, cuy1, cuy2);
        s_cyu1[isy] = coverage(hi, cuy1, cuy2);
        s_cyo0[isy] = coverage(lo, coy1, coy2);
        s_cyo1[isy] = coverage(hi, coy1, coy2);
    }
    __syncthreads();

    const float* fc = feat + (size_t)(bimg * CCH + c) * (H * W);
    float accs[7] = {0,0,0,0,0,0,0};

    #pragma unroll
    for (int isy = 0; isy < 2; ++isy) {
        const int   ylo = s_ylo[isy], yhi = s_yhi[isy];
        const float wyl = s_wyl[isy], wyh = s_wyh[isy];
        const float cyu0 = s_cyu0[isy], cyu1 = s_cyu1[isy];
        const float cyo0 = s_cyo0[isy], cyo1 = s_cyo1[isy];
        const float* rlo = fc + ylo * W;
        const float* rhi = fc + yhi * W;
        #pragma unroll
        for (int ix = 0; ix < 14; ++ix) {
            const int pxb = ix >> 1;
            const int xlo = t_xlo[ix], xhi = t_xhi[ix];
            const float wxl = t_wxl[ix], wxh = t_wxh[ix];
            const float cxu0 = t_cxu0[ix], cxu1 = t_cxu1[ix];
            const float cxo0 = t_cxo0[ix], cxo1 = t_cxo1[ix];
            const float w00 = wyl*wxl*fmaxf(cyu0*cxu0, cyo0*cxo0);
            const float w01 = wyl*wxh*fmaxf(cyu0*cxu1, cyo0*cxo1);
            const float w10 = wyh*wxl*fmaxf(cyu1*cxu0, cyo1*cxo0);
            const float w11 = wyh*wxh*fmaxf(cyu1*cxu1, cyo1*cxo1);
            accs[pxb] += w00*rlo[xlo] + w01*rlo[xhi] + w10*rhi[xlo] + w11*rhi[xhi];
        }
    }

    float* op = out + ((size_t)k * CCH + c) * (PP * PP) + py * PP;
    #pragma unroll
    for (int pxb = 0; pxb < 7; ++pxb) op[pxb] = accs[pxb] * 0.25f;
}

extern "C" void kernel_launch(void* const* d_in, const int* in_sizes, int n_in,
                              void* d_out, int out_size, void* d_ws, size_t ws_size,
                              hipStream_t stream) {
    const float* f0 = (const float*)d_in[0];
    const float* f1 = (const float*)d_in[1];
    const float* f2 = (const float*)d_in[2];
    const float* f3 = (const float*)d_in[3];
    const float* bh = (const float*)d_in[4];
    const float* bo = (const float*)d_in[5];
    float* out = (float*)d_out;
    const int K = in_sizes[4] / 5;
    const int NIMG = in_sizes[0] / (CCH * 128 * 128);

    // NHWC workspace layout (floats): [L0 | L1 | L2 | L3]
    const size_t hw0 = 128*128, hw1 = 64*64, hw2 = 32*32, hw3 = 16*16;
    const size_t sz0 = (size_t)NIMG * CCH * hw0;
    const size_t sz1 = (size_t)NIMG * CCH * hw1;
    const size_t sz2 = (size_t)NIMG * CCH * hw2;
    const size_t sz3 = (size_t)NIMG * CCH * hw3;
    const size_t need_bytes = (sz0 + sz1 + sz2 + sz3) * sizeof(float);

    if (ws_size >= need_bytes) {
        float* w0 = (float*)d_ws;
        float* w1 = w0 + sz0;
        float* w2 = w1 + sz1;
        float* w3 = w2 + sz2;

        const int tiles = NIMG * (1024 + 256 + 64 + 16);
        nchw_to_nhwc_all<<<tiles, 256, 0, stream>>>(f0, f1, f2, f3, w0, w1, w2, w3, NIMG);
        roi_gather_nhwc<<<dim3(K, 2), 448, 0, stream>>>(w0, w1, w2, w3, bh, bo, out, K);
    } else {
        roi_pair_kernel<<<dim3(K, PP), CCH, 0, stream>>>(f0, f1, f2, f3, bh, bo, out, K);
    }
}

// Round 11
// 121.140 us; speedup vs baseline: 1.1198x; 1.1198x over previous
//
#include <hip/hip_runtime.h>
#include <hip/hip_fp16.h>
#include <math.h>

#define PP 7
#define CCH 256

// Fractional per-pixel coverage at integer column `colf` of interval [a,b].
__device__ __forceinline__ float coverage(float colf, float a, float b) {
    float af = floorf(a);
    float bc = ceilf(b);
    float v  = (colf >= af && colf < bc) ? 1.0f : 0.0f;
    float wl = (colf == af) ? (1.0f + af - a) : 1.0f;
    float wr = (colf == bc - 1.0f) ? (1.0f + b - bc) : 1.0f;
    return v * wl * wr;
}

// unpack 4 halfs (carried in a float2) to float4
__device__ __forceinline__ float4 h4f(float2 r) {
    const __half2* h = reinterpret_cast<const __half2*>(&r);
    const float2 a = __half22float2(h[0]);
    const float2 b = __half22float2(h[1]);
    return make_float4(a.x, a.y, b.x, b.y);
}

// ---------------- fused NCHW(f32) -> NHWC(f16) transpose, all 4 levels ----------------
__global__ __launch_bounds__(256) void nchw_to_nhwc_all(
    const float* __restrict__ f0, const float* __restrict__ f1,
    const float* __restrict__ f2, const float* __restrict__ f3,
    __half* __restrict__ w0, __half* __restrict__ w1,
    __half* __restrict__ w2, __half* __restrict__ w3, int NIMG)
{
    __shared__ float tile[64][65];
    int b = blockIdx.x;
    const float* src; __half* dst; int HW, hw64;
    const int t0 = NIMG * 1024, t1 = t0 + NIMG * 256, t2 = t1 + NIMG * 64;
    if (b < t0)      {          src = f0; dst = w0; HW = 16384; hw64 = 256; }
    else if (b < t1) { b -= t0; src = f1; dst = w1; HW = 4096;  hw64 = 64;  }
    else if (b < t2) { b -= t1; src = f2; dst = w2; HW = 1024;  hw64 = 16;  }
    else             { b -= t2; src = f3; dst = w3; HW = 256;   hw64 = 4;   }
    const int tpi  = hw64 * 4;
    const int n    = b / tpi;
    const int r    = b - n * tpi;
    const int cb   = r / hw64;
    const int pix0 = (r - cb * hw64) * 64;
    const int c0   = cb * 64;

    const int tid = threadIdx.x;

    // load phase: float4 of pixels; coalesced along x
    {
        const int pq = tid & 15;          // pixel quad 0..15
        const int chb = tid >> 4;         // 0..15
        const float* s = src + ((size_t)n * CCH + c0) * HW + pix0 + 4*pq;
        #pragma unroll
        for (int it = 0; it < 4; ++it) {
            const int ch = chb + it*16;
            const float4 v = *(const float4*)(s + (size_t)ch * HW);
            tile[ch][4*pq+0] = v.x;
            tile[ch][4*pq+1] = v.y;
            tile[ch][4*pq+2] = v.z;
            tile[ch][4*pq+3] = v.w;
        }
    }
    __syncthreads();
    // store phase: half4 (8 B) of channels; lanes 0..15 cover 128 B of one pixel
    {
        const int tc = tid & 15;          // channel quad 0..15
        const int pb2 = tid >> 4;         // 0..15
        __half* d = dst + ((size_t)n * HW + pix0) * CCH + c0 + 4*tc;
        #pragma unroll
        for (int it = 0; it < 4; ++it) {
            const int p = pb2 + it*16;
            const __half2 lo = __floats2half2_rn(tile[4*tc+0][p], tile[4*tc+1][p]);
            const __half2 hi = __floats2half2_rn(tile[4*tc+2][p], tile[4*tc+3][p]);
            float2 pk;
            *reinterpret_cast<__half2*>(&pk.x) = lo;
            *reinterpret_cast<__half2*>(&pk.y) = hi;
            *(float2*)(d + (size_t)p * CCH) = pk;
        }
    }
}

// ---------------- gather: block = pair k; wave = py; lane = channel-quad (fp16 src) ----------------
__global__ __launch_bounds__(448) void roi_gather_nhwc(
    const __half* __restrict__ n0, const __half* __restrict__ n1,
    const __half* __restrict__ n2, const __half* __restrict__ n3,
    const float* __restrict__ bh, const float* __restrict__ bo,
    float* __restrict__ out, int K)
{
    const int k    = blockIdx.x;
    const int tid  = threadIdx.x;        // 0..447
    const int wpy  = tid >> 6;           // wave id == output bin row 0..6
    const int lane = tid & 63;           // channel quad: c0 = 4*lane

    __shared__ float stage[CCH * 49];                // 50176 B; flat == out[k] layout
    __shared__ float wbin[49][16];                   // per-bin corner weights
    __shared__ int   t_xoff_lo[14], t_xoff_hi[14];   // x*256 (halfs)
    __shared__ int   s_yoff_lo[14], s_yoff_hi[14];   // y*W*256 (halfs)
    __shared__ float t_wxl[14], t_wxh[14], t_cxu0[14], t_cxu1[14], t_cxo0[14], t_cxo1[14];
    __shared__ float t_wyl[14], t_wyh[14], t_cyu0[14], t_cyu1[14], t_cyo0[14], t_cyo1[14];

    // ---- per-box uniform scalar metadata ----
    const float hx1 = bh[k*5+1], hy1 = bh[k*5+2], hx2 = bh[k*5+3], hy2 = bh[k*5+4];
    const float px1 = bo[k*5+1], py1 = bo[k*5+2], px2 = bo[k*5+3], py2 = bo[k*5+4];
    const int   bimg = (int)bh[k*5+0];

    const float ux1 = fminf(hx1, px1), uy1 = fminf(hy1, py1);
    const float ux2 = fmaxf(hx2, px2), uy2 = fmaxf(hy2, py2);
    const float su = sqrtf((ux2-ux1)*(uy2-uy1));
    const float so = sqrtf((px2-px1)*(py2-py1));
    const float s  = fminf(su, so);
    float lvf = floorf(4.0f + log2f(s/224.0f + 1e-6f));
    lvf = fminf(fmaxf(lvf, 2.0f), 5.0f);
    const int lv = (int)lvf - 2;

    const float scales[4] = {0.25f, 0.125f, 0.0625f, 0.03125f};
    const int   dims[4]   = {128, 64, 32, 16};
    const float scale = scales[lv];
    const int   W = dims[lv], H = W;
    const int   HW = W * H;
    const float Wf = (float)W, Hf = (float)H;
    const __half* nh = (lv == 0) ? n0 : (lv == 1) ? n1 : (lv == 2) ? n2 : n3;

    const float usx1 = ux1*scale, usy1 = uy1*scale, usx2 = ux2*scale, usy2 = uy2*scale;
    const float osx1 = px1*scale, osy1 = py1*scale, osx2 = px2*scale, osy2 = py2*scale;
    const float cux1 = fminf(fmaxf(usx1, 0.f), Wf), cux2 = fminf(fmaxf(usx2, 0.f), Wf);
    const float cuy1 = fminf(fmaxf(usy1, 0.f), Hf), cuy2 = fminf(fmaxf(usy2, 0.f), Hf);
    const float cox1 = fminf(fmaxf(osx1, 0.f), Wf), cox2 = fminf(fmaxf(osx2, 0.f), Wf);
    const float coy1 = fminf(fmaxf(osy1, 0.f), Hf), coy2 = fminf(fmaxf(osy2, 0.f), Hf);
    const float roi_w = fmaxf(usx2 - usx1, 1.0f);
    const float roi_h = fmaxf(usy2 - usy1, 1.0f);

    // ---- axis tables (x: wave0 lanes 0..13, y: wave1 lanes 0..13) ----
    if (tid < 14) {
        const int i = tid;
        const float t = (float)(i >> 1) + 0.25f + 0.5f*(float)(i & 1);
        const float p = usx1 + t * (roi_w / 7.0f);
        const float valid = (p >= -1.0f && p <= Wf) ? 1.0f : 0.0f;
        float cc = fmaxf(p, 0.0f);
        const float lo0 = floorf(cc);
        const bool top = (lo0 >= Wf - 1.0f);
        const float lo = top ? (Wf - 1.0f) : lo0;
        const float hi = top ? (Wf - 1.0f) : (lo0 + 1.0f);
        cc = top ? (Wf - 1.0f) : cc;
        const float frac = cc - lo;
        t_xoff_lo[i] = (int)lo * CCH;  t_xoff_hi[i] = (int)hi * CCH;
        t_wxl[i] = (1.0f - frac) * valid;  t_wxh[i] = frac * valid;
        t_cxu0[i] = coverage(lo, cux1, cux2);
        t_cxu1[i] = coverage(hi, cux1, cux2);
        t_cxo0[i] = coverage(lo, cox1, cox2);
        t_cxo1[i] = coverage(hi, cox1, cox2);
    } else if (tid >= 64 && tid < 78) {
        const int i = tid - 64;
        const float t = (float)(i >> 1) + 0.25f + 0.5f*(float)(i & 1);
        const float p = usy1 + t * (roi_h / 7.0f);
        const float valid = (p >= -1.0f && p <= Hf) ? 1.0f : 0.0f;
        float cc = fmaxf(p, 0.0f);
        const float lo0 = floorf(cc);
        const bool top = (lo0 >= Hf - 1.0f);
        const float lo = top ? (Hf - 1.0f) : lo0;
        const float hi = top ? (Hf - 1.0f) : (lo0 + 1.0f);
        cc = top ? (Hf - 1.0f) : cc;
        const float frac = cc - lo;
        s_yoff_lo[i] = (int)lo * W * CCH;  s_yoff_hi[i] = (int)hi * W * CCH;
        t_wyl[i] = (1.0f - frac) * valid;  t_wyh[i] = frac * valid;
        t_cyu0[i] = coverage(lo, cuy1, cuy2);
        t_cyu1[i] = coverage(hi, cuy1, cuy2);
        t_cyo0[i] = coverage(lo, coy1, coy2);
        t_cyo1[i] = coverage(hi, coy1, coy2);
    }
    __syncthreads();

    // ---- per-bin weight table (wave0 lanes 0..48) ----
    if (tid < 49) {
        const int bpy = tid / 7, bpx = tid - bpy * 7;
        #pragma unroll
        for (int isy = 0; isy < 2; ++isy) {
            const int sy = 2*bpy + isy;
            const float wy0 = t_wyl[sy], wy1 = t_wyh[sy];
            const float yu0 = t_cyu0[sy], yu1 = t_cyu1[sy];
            const float yo0 = t_cyo0[sy], yo1 = t_cyo1[sy];
            #pragma unroll
            for (int isx = 0; isx < 2; ++isx) {
                const int sxm = 2*bpx + isx;
                const float wx0 = t_wxl[sxm], wx1 = t_wxh[sxm];
                const float xu0 = t_cxu0[sxm], xu1 = t_cxu1[sxm];
                const float xo0 = t_cxo0[sxm], xo1 = t_cxo1[sxm];
                const int p4 = (isy*2 + isx) * 4;
                wbin[tid][p4+0] = wy0*wx0*fmaxf(yu0*xu0, yo0*xo0);
                wbin[tid][p4+1] = wy0*wx1*fmaxf(yu0*xu1, yo0*xo1);
                wbin[tid][p4+2] = wy1*wx0*fmaxf(yu1*xu0, yo1*xo0);
                wbin[tid][p4+3] = wy1*wx1*fmaxf(yu1*xu1, yo1*xo1);
            }
        }
    }
    __syncthreads();

    // ---- main gather: 8 B half4 per (corner, channel-quad); weights from LDS ----
    const __half* pb = nh + (size_t)bimg * HW * CCH + 4*lane;

    float4 acc[7];
    #pragma unroll
    for (int q = 0; q < 7; ++q) acc[q] = make_float4(0.f, 0.f, 0.f, 0.f);

    #pragma unroll
    for (int isy = 0; isy < 2; ++isy) {
        const int sy  = 2*wpy + isy;
        const int yoL = s_yoff_lo[sy], yoH = s_yoff_hi[sy];
        #pragma unroll
        for (int ix = 0; ix < 14; ++ix) {
            const int pxb = ix >> 1, isx = ix & 1;
            const float4 w = *(const float4*)&wbin[wpy*7 + pxb][(isy*2 + isx)*4];
            const int xoL = t_xoff_lo[ix], xoH = t_xoff_hi[ix];
            const float4 vLL = h4f(*(const float2*)(pb + yoL + xoL));
            const float4 vLH = h4f(*(const float2*)(pb + yoL + xoH));
            const float4 vHL = h4f(*(const float2*)(pb + yoH + xoL));
            const float4 vHH = h4f(*(const float2*)(pb + yoH + xoH));
            acc[pxb].x += w.x*vLL.x + w.y*vLH.x + w.z*vHL.x + w.w*vHH.x;
            acc[pxb].y += w.x*vLL.y + w.y*vLH.y + w.z*vHL.y + w.w*vHH.y;
            acc[pxb].z += w.x*vLL.z + w.y*vLH.z + w.z*vHL.z + w.w*vHH.z;
            acc[pxb].w += w.x*vLL.w + w.y*vLH.w + w.z*vHL.w + w.w*vHH.w;
        }
    }

    // ---- stage results: stage flat layout == out[k] flat layout (c*49 + py*7 + px) ----
    {
        const int c0 = 4*lane;
        #pragma unroll
        for (int q = 0; q < 7; ++q) {
            const int col = wpy*7 + q;
            stage[(c0+0)*49 + col] = acc[q].x * 0.25f;
            stage[(c0+1)*49 + col] = acc[q].y * 0.25f;
            stage[(c0+2)*49 + col] = acc[q].z * 0.25f;
            stage[(c0+3)*49 + col] = acc[q].w * 0.25f;
        }
    }
    __syncthreads();

    // ---- single coalesced burst: 12544 floats, each line written once ----
    float* ok = out + (size_t)k * (CCH * 49);
    #pragma unroll
    for (int i = 0; i < 28; ++i) {
        const int idx = tid + i*448;
        ok[idx] = stage[idx];
    }
}

// ---------------- fallback: measured-good NCHW direct kernel (291 us) ----------------
__global__ __launch_bounds__(256) void roi_pair_kernel(
    const float* __restrict__ f0, const float* __restrict__ f1,
    const float* __restrict__ f2, const float* __restrict__ f3,
    const float* __restrict__ bh, const float* __restrict__ bo,
    float* __restrict__ out, int K)
{
    const int k  = blockIdx.x;
    const int py = blockIdx.y;
    const int c  = threadIdx.x;

    __shared__ int   t_xlo[14], t_xhi[14];
    __shared__ float t_wxl[14], t_wxh[14], t_cxu0[14], t_cxu1[14], t_cxo0[14], t_cxo1[14];
    __shared__ int   s_ylo[2], s_yhi[2];
    __shared__ float s_wyl[2], s_wyh[2], s_cyu0[2], s_cyu1[2], s_cyo0[2], s_cyo1[2];

    const float hx1 = bh[k*5+1], hy1 = bh[k*5+2], hx2 = bh[k*5+3], hy2 = bh[k*5+4];
    const float px1 = bo[k*5+1], py1 = bo[k*5+2], px2 = bo[k*5+3], py2 = bo[k*5+4];
    const int   bimg = (int)bh[k*5+0];

    const float ux1 = fminf(hx1, px1), uy1 = fminf(hy1, py1);
    const float ux2 = fmaxf(hx2, px2), uy2 = fmaxf(hy2, py2);
    const float su = sqrtf((ux2-ux1)*(uy2-uy1));
    const float so = sqrtf((px2-px1)*(py2-py1));
    const float s  = fminf(su, so);
    float lvf = floorf(4.0f + log2f(s/224.0f + 1e-6f));
    lvf = fminf(fmaxf(lvf, 2.0f), 5.0f);
    const int lv = (int)lvf - 2;

    const float scales[4] = {0.25f, 0.125f, 0.0625f, 0.03125f};
    const int   dims[4]   = {128, 64, 32, 16};
    const float scale = scales[lv];
    const int   W = dims[lv], H = W;
    const float Wf = (float)W, Hf = (float)H;
    const float* feat = (lv == 0) ? f0 : (lv == 1) ? f1 : (lv == 2) ? f2 : f3;

    const float usx1 = ux1*scale, usy1 = uy1*scale, usx2 = ux2*scale, usy2 = uy2*scale;
    const float osx1 = px1*scale, osy1 = py1*scale, osx2 = px2*scale, osy2 = py2*scale;
    const float cux1 = fminf(fmaxf(usx1, 0.f), Wf), cux2 = fminf(fmaxf(usx2, 0.f), Wf);
    const float cuy1 = fminf(fmaxf(usy1, 0.f), Hf), cuy2 = fminf(fmaxf(usy2, 0.f), Hf);
    const float cox1 = fminf(fmaxf(osx1, 0.f), Wf), cox2 = fminf(fmaxf(osx2, 0.f), Wf);
    const float coy1 = fminf(fmaxf(osy1, 0.f), Hf), coy2 = fminf(fmaxf(osy2, 0.f), Hf);
    const float roi_w = fmaxf(usx2 - usx1, 1.0f);
    const float roi_h = fmaxf(usy2 - usy1, 1.0f);

    if (threadIdx.x < 14) {
        const int i = threadIdx.x;
        const float t = (float)(i >> 1) + 0.25f + 0.5f*(float)(i & 1);
        const float p = usx1 + t * (roi_w / 7.0f);
        const float valid = (p >= -1.0f && p <= Wf) ? 1.0f : 0.0f;
        float cc = fmaxf(p, 0.0f);
        const float lo0 = floorf(cc);
        const bool top = (lo0 >= Wf - 1.0f);
        const float lo = top ? (Wf - 1.0f) : lo0;
        const float hi = top ? (Wf - 1.0f) : (lo0 + 1.0f);
        cc = top ? (Wf - 1.0f) : cc;
        const float frac = cc - lo;
        t_xlo[i] = (int)lo;  t_xhi[i] = (int)hi;
        t_wxl[i] = (1.0f - frac) * valid;  t_wxh[i] = frac * valid;
        t_cxu0[i] = coverage(lo, cux1, cux2);
        t_cxu1[i] = coverage(hi, cux1, cux2);
        t_cxo0[i] = coverage(lo, cox1, cox2);
        t_cxo1[i] = coverage(hi, cox1, cox2);
    } else if (threadIdx.x >= 64 && threadIdx.x < 66) {
        const int isy = threadIdx.x - 64;
        const int i = 2*py + isy;
        const float t = (float)(i >> 1) + 0.25f + 0.5f*(float)(i & 1);
        const float p = usy1 + t * (roi_h / 7.0f);
        const float valid = (p >= -1.0f && p <= Hf) ? 1.0f : 0.0f;
        float cc = fmaxf(p, 0.0f);
        const float lo0 = floorf(cc);
        const bool top = (lo0 >= Hf - 1.0f);
        const float lo = top ? (Hf - 1.0f) : lo0;
        const float hi = top ? (Hf - 1.0f) : (lo0 + 1.0f);
        cc = top ? (Hf - 1.0f) : cc;
        const float frac = cc - lo;
        s_ylo[isy] = (int)lo;  s_yhi[isy] = (int)hi;
        s_wyl[isy] = (1.0f - frac) * valid;  s_wyh[isy] = frac * valid;
        s_cyu0[isy] = coverage(lo, cuy1, cuy2);
        s_cyu1[isy] = coverage(hi, cuy1, cuy2);
        s_cyo0[isy] = coverage(lo, coy1, coy2);
        s_cyo1[isy] = coverage(hi, coy1, coy2);
    }
    __syncthreads();

    const float* fc = feat + (size_t)(bimg * CCH + c) * (H * W);
    float accs[7] = {0,0,0,0,0,0,0};

    #pragma unroll
    for (int isy = 0; isy < 2; ++isy) {
        const int   ylo = s_ylo[isy], yhi = s_yhi[isy];
        const float wyl = s_wyl[isy], wyh = s_wyh[isy];
        const float cyu0 = s_cyu0[isy], cyu1 = s_cyu1[isy];
        const float cyo0 = s_cyo0[isy], cyo1 = s_cyo1[isy];
        const float* rlo = fc + ylo * W;
        const float* rhi = fc + yhi * W;
        #pragma unroll
        for (int ix = 0; ix < 14; ++ix) {
            const int pxb = ix >> 1;
            const int xlo = t_xlo[ix], xhi = t_xhi[ix];
            const float wxl = t_wxl[ix], wxh = t_wxh[ix];
            const float cxu0 = t_cxu0[ix], cxu1 = t_cxu1[ix];
            const float cxo0 = t_cxo0[ix], cxo1 = t_cxo1[ix];
            const float w00 = wyl*wxl*fmaxf(cyu0*cxu0, cyo0*cxo0);
            const float w01 = wyl*wxh*fmaxf(cyu0*cxu1, cyo0*cxo1);
            const float w10 = wyh*wxl*fmaxf(cyu1*cxu0, cyo1*cxo0);
            const float w11 = wyh*wxh*fmaxf(cyu1*cxu1, cyo1*cxo1);
            accs[pxb] += w00*rlo[xlo] + w01*rlo[xhi] + w10*rhi[xlo] + w11*rhi[xhi];
        }
    }

    float* op = out + ((size_t)k * CCH + c) * (PP * PP) + py * PP;
    #pragma unroll
    for (int pxb = 0; pxb < 7; ++pxb) op[pxb] = accs[pxb] * 0.25f;
}

extern "C" void kernel_launch(void* const* d_in, const int* in_sizes, int n_in,
                              void* d_out, int out_size, void* d_ws, size_t ws_size,
                              hipStream_t stream) {
    const float* f0 = (const float*)d_in[0];
    const float* f1 = (const float*)d_in[1];
    const float* f2 = (const float*)d_in[2];
    const float* f3 = (const float*)d_in[3];
    const float* bh = (const float*)d_in[4];
    const float* bo = (const float*)d_in[5];
    float* out = (float*)d_out;
    const int K = in_sizes[4] / 5;
    const int NIMG = in_sizes[0] / (CCH * 128 * 128);

    // NHWC(f16) workspace layout (halfs): [L0 | L1 | L2 | L3]
    const size_t hw0 = 128*128, hw1 = 64*64, hw2 = 32*32, hw3 = 16*16;
    const size_t sz0 = (size_t)NIMG * CCH * hw0;
    const size_t sz1 = (size_t)NIMG * CCH * hw1;
    const size_t sz2 = (size_t)NIMG * CCH * hw2;
    const size_t sz3 = (size_t)NIMG * CCH * hw3;
    const size_t need_bytes = (sz0 + sz1 + sz2 + sz3) * sizeof(__half);

    if (ws_size >= need_bytes) {
        __half* w0 = (__half*)d_ws;
        __half* w1 = w0 + sz0;
        __half* w2 = w1 + sz1;
        __half* w3 = w2 + sz2;

        const int tiles = NIMG * (1024 + 256 + 64 + 16);
        nchw_to_nhwc_all<<<tiles, 256, 0, stream>>>(f0, f1, f2, f3, w0, w1, w2, w3, NIMG);
        roi_gather_nhwc<<<K, 448, 0, stream>>>(w0, w1, w2, w3, bh, bo, out, K);
    } else {
        roi_pair_kernel<<<dim3(K, PP), CCH, 0, stream>>>(f0, f1, f2, f3, bh, bo, out, K);
    }
}